// Round 2
// baseline (2180.750 us; speedup 1.0000x reference)
//
#include <hip/hip_runtime.h>
#include <hip/hip_bf16.h>
#include <math.h>

#define CH 64

__device__ __forceinline__ float bf2f(unsigned short u) {
    return __uint_as_float(((unsigned int)u) << 16);
}

// ---------------------------------------------------------------------------
// Dtype detector: decide whether float tensors are bf16 (flag=1) or fp32
// (flag=0) by exponent-sanity voting on x's first 64 fp32-slots.
// fp32 raw mantissa words (even ushorts) have random/zero exponents -> insane.
// ---------------------------------------------------------------------------
__global__ void k_detect(const unsigned short* __restrict__ x, int* __restrict__ flag)
{
    int lane = threadIdx.x;                 // 64 threads
    unsigned short u = x[2 * lane];         // even positions
    int e = (u >> 7) & 0xFF;
    bool insane = (e < 0x60) || (e > 0x9F); // |v| outside [2^-31, 2^32]
    unsigned long long m = __ballot(insane);
    if (lane == 0) flag[0] = (__popcll(m) > 16) ? 0 : 1;
}

// ---------------------------------------------------------------------------
// Scatter-add x[src] into agg[dst] (fp32 atomics); optionally count degree.
// MODE: 0 = x dtype per flag, 1 = x always bf16 (hidden state h).
// 16 threads per edge, 4 channels each.
// ---------------------------------------------------------------------------
template <int MODE, bool COUNT>
__global__ __launch_bounds__(256) void k_scatter(
    const int* __restrict__ flag, const void* __restrict__ xin,
    const int* __restrict__ srcs, const int* __restrict__ dsts,
    float* __restrict__ agg, float* __restrict__ cnt,
    int n_edges, int n_nodes)
{
    int tid = blockIdx.x * 256 + threadIdx.x;
    int e = tid >> 4, g = tid & 15;
    if (e >= n_edges) return;
    int s = srcs[e], d = dsts[e];
    if ((unsigned)s >= (unsigned)n_nodes || (unsigned)d >= (unsigned)n_nodes) return;
    float v0, v1, v2, v3;
    bool isbf = (MODE == 1) ? true : (flag[0] != 0);
    if (isbf) {
        ushort4 u = *(const ushort4*)((const unsigned short*)xin + (size_t)s * CH + g * 4);
        v0 = bf2f(u.x); v1 = bf2f(u.y); v2 = bf2f(u.z); v3 = bf2f(u.w);
    } else {
        float4 f = *(const float4*)((const float*)xin + (size_t)s * CH + g * 4);
        v0 = f.x; v1 = f.y; v2 = f.z; v3 = f.w;
    }
    float* ap = agg + (size_t)d * CH + g * 4;
    atomicAdd(ap + 0, v0);
    atomicAdd(ap + 1, v1);
    atomicAdd(ap + 2, v2);
    atomicAdd(ap + 3, v3);
    if (COUNT && g == 0) atomicAdd(cnt + d, 1.0f);
}

// ---------------------------------------------------------------------------
// h = relu( (agg/max(cnt,1)) @ w_l^T + b + x @ w_r^T ), h stored bf16.
// One wave per node; lane = output channel. Weights staged fp32 in LDS,
// transposed (wT[k*64+o] = w[o][k]) so lane reads are conflict-free.
// XH: true  -> xin is bf16 hidden state (layer 2)
//     false -> xin dtype per flag (layer 1 input x)
// ---------------------------------------------------------------------------
template <bool XH>
__global__ __launch_bounds__(256) void k_sage(
    const int* __restrict__ flag, const void* __restrict__ xin,
    const float* __restrict__ agg, const float* __restrict__ cnt,
    const void* __restrict__ w_l, const void* __restrict__ bias,
    const void* __restrict__ w_r,
    __hip_bfloat16* __restrict__ hout, int n_nodes)
{
    __shared__ float wlT[CH * CH];
    __shared__ float wrT[CH * CH];
    __shared__ float bs[CH];
    int isbf = flag[0];
    {
        const unsigned short* wlu = (const unsigned short*)w_l;
        const unsigned short* wru = (const unsigned short*)w_r;
        const float* wlf = (const float*)w_l;
        const float* wrf = (const float*)w_r;
        for (int i = threadIdx.x; i < CH * CH; i += 256) {
            int o = i >> 6, k = i & 63;      // w[o][k] row-major
            wlT[k * CH + o] = isbf ? bf2f(wlu[i]) : wlf[i];
            wrT[k * CH + o] = isbf ? bf2f(wru[i]) : wrf[i];
        }
        if (threadIdx.x < CH) {
            bs[threadIdx.x] = isbf ? bf2f(((const unsigned short*)bias)[threadIdx.x])
                                   : ((const float*)bias)[threadIdx.x];
        }
    }
    __syncthreads();

    int lane = threadIdx.x & 63;
    int gw = (blockIdx.x * 256 + threadIdx.x) >> 6;
    int nw = gridDim.x * 4;
    for (int node = gw; node < n_nodes; node += nw) {
        size_t base = (size_t)node * CH;
        float inv = 1.0f / fmaxf(cnt[node], 1.0f);
        float m = agg[base + lane] * inv;
        float xv;
        if (XH) {
            xv = bf2f(((const unsigned short*)xin)[base + lane]);
        } else {
            xv = isbf ? bf2f(((const unsigned short*)xin)[base + lane])
                      : ((const float*)xin)[base + lane];
        }
        float acc = bs[lane];
        #pragma unroll
        for (int j = 0; j < CH; j++) {
            acc = fmaf(__shfl(m,  j), wlT[j * CH + lane], acc);
            acc = fmaf(__shfl(xv, j), wrT[j * CH + lane], acc);
        }
        hout[base + lane] = __float2bfloat16(fmaxf(acc, 0.0f));
    }
}

// ---------------------------------------------------------------------------
// out = sigmoid(h @ w_out^T + b_out); h is bf16; out dtype follows flag.
// One wave per node, butterfly reduce.
// ---------------------------------------------------------------------------
__global__ __launch_bounds__(256) void k_final(
    const int* __restrict__ flag, const __hip_bfloat16* __restrict__ h,
    const void* __restrict__ w_out, const void* __restrict__ b_out,
    void* __restrict__ out, int n_nodes)
{
    int gw = (blockIdx.x * 256 + threadIdx.x) >> 6;
    int lane = threadIdx.x & 63;
    if (gw >= n_nodes) return;
    int isbf = flag[0];
    float hv = bf2f(((const unsigned short*)h)[(size_t)gw * CH + lane]);
    float wv = isbf ? bf2f(((const unsigned short*)w_out)[lane])
                    : ((const float*)w_out)[lane];
    float v = hv * wv;
    #pragma unroll
    for (int off = 32; off; off >>= 1) v += __shfl_xor(v, off);
    if (lane == 0) {
        float b = isbf ? bf2f(((const unsigned short*)b_out)[0])
                       : ((const float*)b_out)[0];
        float z = v + b;
        float sg = 1.0f / (1.0f + expf(-z));
        if (isbf) ((__hip_bfloat16*)out)[gw] = __float2bfloat16(sg);
        else      ((float*)out)[gw] = sg;
    }
}

extern "C" void kernel_launch(void* const* d_in, const int* in_sizes, int n_in,
                              void* d_out, int out_size, void* d_ws, size_t ws_size,
                              hipStream_t stream)
{
    const void* x    = d_in[0];
    const int*  ei   = (const int*)d_in[1];
    const void* w1_l = d_in[2];
    const void* b1   = d_in[3];
    const void* w1_r = d_in[4];
    const void* w2_l = d_in[5];
    const void* b2   = d_in[6];
    const void* w2_r = d_in[7];
    const void* wout = d_in[8];
    const void* bout = d_in[9];

    int n_nodes = out_size;            // output is (N,1)
    int n_edges = in_sizes[1] / 2;
    const int* srcs = ei;
    const int* dsts = ei + n_edges;

    // ws layout (256B-aligned regions): [flag][cnt n f32][agg n*64 f32][h n*64 bf16]
    char* wsb = (char*)d_ws;
    size_t off = 0;
    auto carve = [&](size_t bytes) { size_t p = off; off = (off + bytes + 255) & ~(size_t)255; return p; };
    size_t flag_off = carve(sizeof(int));
    size_t cnt_off  = carve((size_t)n_nodes * sizeof(float));
    size_t agg_off  = carve((size_t)n_nodes * CH * sizeof(float));
    size_t h_off    = carve((size_t)n_nodes * CH * sizeof(__hip_bfloat16));
    int*   flag = (int*)(wsb + flag_off);
    float* cnt  = (float*)(wsb + cnt_off);
    float* agg  = (float*)(wsb + agg_off);
    __hip_bfloat16* h = (__hip_bfloat16*)(wsb + h_off);

    int sblocks = (n_edges * 16 + 255) / 256;
    int gblocks = 1024;
    int fblocks = (n_nodes + 3) / 4;

    k_detect<<<1, 64, 0, stream>>>((const unsigned short*)x, flag);

    // zero cnt + agg in one shot (they are adjacent; alignment gap harmless)
    hipMemsetAsync(wsb + cnt_off, 0, agg_off + (size_t)n_nodes * CH * sizeof(float) - cnt_off, stream);

    // layer 1
    k_scatter<0, true><<<sblocks, 256, 0, stream>>>(flag, x, srcs, dsts, agg, cnt, n_edges, n_nodes);
    k_sage<false><<<gblocks, 256, 0, stream>>>(flag, x, agg, cnt, w1_l, b1, w1_r, h, n_nodes);

    // layer 2 (h in-place is safe: each wave touches only its own node row)
    hipMemsetAsync(agg, 0, (size_t)n_nodes * CH * sizeof(float), stream);
    k_scatter<1, false><<<sblocks, 256, 0, stream>>>(flag, h, srcs, dsts, agg, nullptr, n_edges, n_nodes);
    k_sage<true><<<gblocks, 256, 0, stream>>>(flag, h, agg, cnt, w2_l, b2, w2_r, h, n_nodes);

    // head
    k_final<<<fblocks, 256, 0, stream>>>(flag, h, wout, bout, d_out, n_nodes);
}

// Round 3
// 798.926 us; speedup vs baseline: 2.7296x; 2.7296x over previous
//
#include <hip/hip_runtime.h>
#include <hip/hip_bf16.h>
#include <math.h>

#define CH 64

__device__ __forceinline__ float bf2f(unsigned short u) {
    return __uint_as_float(((unsigned int)u) << 16);
}

// ---------------------------------------------------------------------------
// Dtype detector: bf16 (flag=1) vs fp32 (flag=0) via exponent-sanity voting.
// ---------------------------------------------------------------------------
__global__ void k_detect(const unsigned short* __restrict__ x, int* __restrict__ flag)
{
    int lane = threadIdx.x;                 // 64 threads
    unsigned short u = x[2 * lane];
    int e = (u >> 7) & 0xFF;
    bool insane = (e < 0x60) || (e > 0x9F);
    unsigned long long m = __ballot(insane);
    if (lane == 0) flag[0] = (__popcll(m) > 16) ? 0 : 1;
}

// ---------------------------------------------------------------------------
// CSR construction: histogram -> 3-step exclusive scan -> permute
// ---------------------------------------------------------------------------
__global__ __launch_bounds__(256) void k_hist(
    const int* __restrict__ dsts, int* __restrict__ deg, int n_edges, int n_nodes)
{
    int e = blockIdx.x * 256 + threadIdx.x;
    if (e >= n_edges) return;
    int d = dsts[e];
    if ((unsigned)d < (unsigned)n_nodes) atomicAdd(&deg[d], 1);
}

// block b scans deg[b*1024 .. b*1024+1023] -> exclusive partials + block total
__global__ __launch_bounds__(256) void k_scan1(
    const int* __restrict__ deg, int* __restrict__ rowptr,
    int* __restrict__ bsum, int n)
{
    __shared__ int ts[256];
    int t = threadIdx.x;
    int base = blockIdx.x * 1024 + t * 4;
    int v[4], local = 0;
    #pragma unroll
    for (int k = 0; k < 4; k++) { v[k] = (base + k < n) ? deg[base + k] : 0; local += v[k]; }
    ts[t] = local; __syncthreads();
    for (int off = 1; off < 256; off <<= 1) {
        int val = (t >= off) ? ts[t - off] : 0;
        __syncthreads();
        ts[t] += val;
        __syncthreads();
    }
    int run = ts[t] - local;
    #pragma unroll
    for (int k = 0; k < 4; k++) { if (base + k < n) rowptr[base + k] = run; run += v[k]; }
    if (t == 255) bsum[blockIdx.x] = ts[255];
}

// single block: exclusive scan of up to 1024 block sums, in place
__global__ __launch_bounds__(256) void k_scan2(int* __restrict__ bsum, int nb)
{
    __shared__ int ts[256];
    int t = threadIdx.x;
    int base = t * 4;
    int v[4], local = 0;
    #pragma unroll
    for (int k = 0; k < 4; k++) { v[k] = (base + k < nb) ? bsum[base + k] : 0; local += v[k]; }
    ts[t] = local; __syncthreads();
    for (int off = 1; off < 256; off <<= 1) {
        int val = (t >= off) ? ts[t - off] : 0;
        __syncthreads();
        ts[t] += val;
        __syncthreads();
    }
    int run = ts[t] - local;
    #pragma unroll
    for (int k = 0; k < 4; k++) { if (base + k < nb) bsum[base + k] = run; run += v[k]; }
}

__global__ __launch_bounds__(256) void k_scan3(
    int* __restrict__ rowptr, int* __restrict__ cursor,
    const int* __restrict__ bsum, int n)
{
    int add = bsum[blockIdx.x];
    int base = blockIdx.x * 1024 + threadIdx.x * 4;
    #pragma unroll
    for (int k = 0; k < 4; k++) {
        int i = base + k;
        if (i < n) { int r = rowptr[i] + add; rowptr[i] = r; cursor[i] = r; }
    }
}

__global__ __launch_bounds__(256) void k_permute(
    const int* __restrict__ srcs, const int* __restrict__ dsts,
    int* __restrict__ cursor, int* __restrict__ nbr, int n_edges, int n_nodes)
{
    int e = blockIdx.x * 256 + threadIdx.x;
    if (e >= n_edges) return;
    int s = srcs[e], d = dsts[e];
    if ((unsigned)s >= (unsigned)n_nodes || (unsigned)d >= (unsigned)n_nodes) return;
    int pos = atomicAdd(&cursor[d], 1);
    nbr[pos] = s;
}

// ---------------------------------------------------------------------------
// Fused SAGE layer: gather-mean over CSR neighbors + dual GEMV + bias + ReLU.
// One wave per node; lane = output channel. Weights staged fp32 in LDS,
// transposed (wT[k*64+o] = w[o][k]).
// XMODE 0: xin dtype per flag (layer-1 input x). XMODE 1: xin is bf16 h.
// HEAD: fuse final linear+sigmoid, write out[node] instead of h row.
// ---------------------------------------------------------------------------
template <int XMODE, bool HEAD>
__global__ __launch_bounds__(256) void k_sage(
    const int* __restrict__ flag, const void* __restrict__ xin,
    const int* __restrict__ nbr, const int* __restrict__ rowptr,
    const int* __restrict__ deg,
    const void* __restrict__ w_l, const void* __restrict__ bias,
    const void* __restrict__ w_r,
    const void* __restrict__ w_out, const void* __restrict__ b_out,
    void* __restrict__ outp, int n_nodes)
{
    __shared__ float wlT[CH * CH];
    __shared__ float wrT[CH * CH];
    __shared__ float bs[CH];
    __shared__ float wo[CH];
    int isbf = flag[0];
    {
        const unsigned short* wlu = (const unsigned short*)w_l;
        const unsigned short* wru = (const unsigned short*)w_r;
        const float* wlf = (const float*)w_l;
        const float* wrf = (const float*)w_r;
        for (int i = threadIdx.x; i < CH * CH; i += 256) {
            int o = i >> 6, k = i & 63;          // w[o][k] row-major
            wlT[k * CH + o] = isbf ? bf2f(wlu[i]) : wlf[i];
            wrT[k * CH + o] = isbf ? bf2f(wru[i]) : wrf[i];
        }
        if (threadIdx.x < CH) {
            bs[threadIdx.x] = isbf ? bf2f(((const unsigned short*)bias)[threadIdx.x])
                                   : ((const float*)bias)[threadIdx.x];
            if (HEAD)
                wo[threadIdx.x] = isbf ? bf2f(((const unsigned short*)w_out)[threadIdx.x])
                                       : ((const float*)w_out)[threadIdx.x];
        }
    }
    __syncthreads();

    int lane = threadIdx.x & 63;
    int gw = (blockIdx.x * 256 + threadIdx.x) >> 6;
    int nw = gridDim.x * 4;
    bool xbf = (XMODE == 1) ? true : (isbf != 0);
    const unsigned short* xu = (const unsigned short*)xin;
    const float* xf = (const float*)xin;

    for (int node = gw; node < n_nodes; node += nw) {
        size_t base = (size_t)node * CH;
        int row = rowptr[node];
        int d = deg[node];

        // gather-mean of neighbor rows
        float aggv = 0.0f;
        for (int b0 = 0; b0 < d; b0 += 64) {
            int idx = (b0 + lane < d) ? nbr[row + b0 + lane] : 0;
            int lim = min(64, d - b0);
            for (int j = 0; j < lim; j++) {
                int s = __shfl(idx, j);
                aggv += xbf ? bf2f(xu[(size_t)s * CH + lane])
                            : xf[(size_t)s * CH + lane];
            }
        }
        float m = aggv / (float)max(d, 1);
        float xv = xbf ? bf2f(xu[base + lane]) : xf[base + lane];

        float acc = bs[lane];
        #pragma unroll
        for (int j = 0; j < CH; j++) {
            acc = fmaf(__shfl(m,  j), wlT[j * CH + lane], acc);
            acc = fmaf(__shfl(xv, j), wrT[j * CH + lane], acc);
        }
        float hv = fmaxf(acc, 0.0f);

        if (HEAD) {
            float v = hv * wo[lane];
            #pragma unroll
            for (int off = 32; off; off >>= 1) v += __shfl_xor(v, off);
            if (lane == 0) {
                float b = isbf ? bf2f(((const unsigned short*)b_out)[0])
                               : ((const float*)b_out)[0];
                float sg = 1.0f / (1.0f + expf(-(v + b)));
                if (isbf) ((__hip_bfloat16*)outp)[node] = __float2bfloat16(sg);
                else      ((float*)outp)[node] = sg;
            }
        } else {
            ((__hip_bfloat16*)outp)[base + lane] = __float2bfloat16(hv);
        }
    }
}

extern "C" void kernel_launch(void* const* d_in, const int* in_sizes, int n_in,
                              void* d_out, int out_size, void* d_ws, size_t ws_size,
                              hipStream_t stream)
{
    const void* x    = d_in[0];
    const int*  ei   = (const int*)d_in[1];
    const void* w1_l = d_in[2];
    const void* b1   = d_in[3];
    const void* w1_r = d_in[4];
    const void* w2_l = d_in[5];
    const void* b2   = d_in[6];
    const void* w2_r = d_in[7];
    const void* wout = d_in[8];
    const void* bout = d_in[9];

    int n_nodes = out_size;            // output is (N,1)
    int n_edges = in_sizes[1] / 2;
    const int* srcs = ei;
    const int* dsts = ei + n_edges;

    // ws layout: [flag][deg n][rowptr n][cursor n][bsum 1024][nbr E][h n*64 bf16]
    char* wsb = (char*)d_ws;
    size_t off = 0;
    auto carve = [&](size_t bytes) { size_t p = off; off = (off + bytes + 255) & ~(size_t)255; return p; };
    size_t flag_off = carve(sizeof(int));
    size_t deg_off  = carve((size_t)n_nodes * sizeof(int));
    size_t row_off  = carve((size_t)n_nodes * sizeof(int));
    size_t cur_off  = carve((size_t)n_nodes * sizeof(int));
    size_t bs_off   = carve(1024 * sizeof(int));
    size_t nbr_off  = carve((size_t)n_edges * sizeof(int));
    size_t h_off    = carve((size_t)n_nodes * CH * sizeof(__hip_bfloat16));
    int* flag   = (int*)(wsb + flag_off);
    int* deg    = (int*)(wsb + deg_off);
    int* rowptr = (int*)(wsb + row_off);
    int* cursor = (int*)(wsb + cur_off);
    int* bsum   = (int*)(wsb + bs_off);
    int* nbr    = (int*)(wsb + nbr_off);
    __hip_bfloat16* h = (__hip_bfloat16*)(wsb + h_off);

    int eblocks = (n_edges + 255) / 256;
    int nb1     = (n_nodes + 1023) / 1024;
    int gblocks = 1024;

    k_detect<<<1, 64, 0, stream>>>((const unsigned short*)x, flag);
    hipMemsetAsync(deg, 0, (size_t)n_nodes * sizeof(int), stream);

    // CSR build
    k_hist<<<eblocks, 256, 0, stream>>>(dsts, deg, n_edges, n_nodes);
    k_scan1<<<nb1, 256, 0, stream>>>(deg, rowptr, bsum, n_nodes);
    k_scan2<<<1, 256, 0, stream>>>(bsum, nb1);
    k_scan3<<<nb1, 256, 0, stream>>>(rowptr, cursor, bsum, n_nodes);
    k_permute<<<eblocks, 256, 0, stream>>>(srcs, dsts, cursor, nbr, n_edges, n_nodes);

    // layer 1: x -> h (bf16)
    k_sage<0, false><<<gblocks, 256, 0, stream>>>(flag, x, nbr, rowptr, deg,
        w1_l, b1, w1_r, nullptr, nullptr, h, n_nodes);
    // layer 2 + head: h -> out
    k_sage<1, true><<<gblocks, 256, 0, stream>>>(flag, h, nbr, rowptr, deg,
        w2_l, b2, w2_r, wout, bout, d_out, n_nodes);
}

// Round 4
// 429.713 us; speedup vs baseline: 5.0749x; 1.8592x over previous
//
#include <hip/hip_runtime.h>
#include <hip/hip_bf16.h>
#include <math.h>

#define CH 64
#define TILE 16
#define TROW 72   // LDS tile row stride (bf16 elems): 144 B, 16B-aligned, not %128B

typedef short short8 __attribute__((ext_vector_type(8)));
typedef float floatx4 __attribute__((ext_vector_type(4)));

__device__ __forceinline__ float bf2f(unsigned short u) {
    return __uint_as_float(((unsigned int)u) << 16);
}
__device__ __forceinline__ unsigned short f2bf(float f) {
    unsigned int x = __float_as_uint(f);
    unsigned int r = (x + 0x7fff + ((x >> 16) & 1)) >> 16;   // RNE
    return (unsigned short)r;
}

// ---------------------------------------------------------------------------
// Dtype detector: bf16 (flag=1) vs fp32 (flag=0) via exponent-sanity voting.
// ---------------------------------------------------------------------------
__global__ void k_detect(const unsigned short* __restrict__ x, int* __restrict__ flag)
{
    int lane = threadIdx.x;
    unsigned short u = x[2 * lane];
    int e = (u >> 7) & 0xFF;
    bool insane = (e < 0x60) || (e > 0x9F);
    unsigned long long m = __ballot(insane);
    if (lane == 0) flag[0] = (__popcll(m) > 16) ? 0 : 1;
}

// ---------------------------------------------------------------------------
// CSR construction: histogram -> 3-step exclusive scan -> permute
// ---------------------------------------------------------------------------
__global__ __launch_bounds__(256) void k_hist(
    const int* __restrict__ dsts, int* __restrict__ deg, int n_edges, int n_nodes)
{
    int e = blockIdx.x * 256 + threadIdx.x;
    if (e >= n_edges) return;
    int d = dsts[e];
    if ((unsigned)d < (unsigned)n_nodes) atomicAdd(&deg[d], 1);
}

__global__ __launch_bounds__(256) void k_scan1(
    const int* __restrict__ deg, int* __restrict__ rowptr,
    int* __restrict__ bsum, int n)
{
    __shared__ int ts[256];
    int t = threadIdx.x;
    int base = blockIdx.x * 1024 + t * 4;
    int v[4], local = 0;
    #pragma unroll
    for (int k = 0; k < 4; k++) { v[k] = (base + k < n) ? deg[base + k] : 0; local += v[k]; }
    ts[t] = local; __syncthreads();
    for (int off = 1; off < 256; off <<= 1) {
        int val = (t >= off) ? ts[t - off] : 0;
        __syncthreads();
        ts[t] += val;
        __syncthreads();
    }
    int run = ts[t] - local;
    #pragma unroll
    for (int k = 0; k < 4; k++) { if (base + k < n) rowptr[base + k] = run; run += v[k]; }
    if (t == 255) bsum[blockIdx.x] = ts[255];
}

__global__ __launch_bounds__(256) void k_scan2(int* __restrict__ bsum, int nb)
{
    __shared__ int ts[256];
    int t = threadIdx.x;
    int base = t * 4;
    int v[4], local = 0;
    #pragma unroll
    for (int k = 0; k < 4; k++) { v[k] = (base + k < nb) ? bsum[base + k] : 0; local += v[k]; }
    ts[t] = local; __syncthreads();
    for (int off = 1; off < 256; off <<= 1) {
        int val = (t >= off) ? ts[t - off] : 0;
        __syncthreads();
        ts[t] += val;
        __syncthreads();
    }
    int run = ts[t] - local;
    #pragma unroll
    for (int k = 0; k < 4; k++) { if (base + k < nb) bsum[base + k] = run; run += v[k]; }
}

__global__ __launch_bounds__(256) void k_scan3(
    int* __restrict__ rowptr, int* __restrict__ cursor,
    const int* __restrict__ bsum, int n)
{
    int add = bsum[blockIdx.x];
    int base = blockIdx.x * 1024 + threadIdx.x * 4;
    #pragma unroll
    for (int k = 0; k < 4; k++) {
        int i = base + k;
        if (i < n) { int r = rowptr[i] + add; rowptr[i] = r; cursor[i] = r; }
    }
}

__global__ __launch_bounds__(256) void k_permute(
    const int* __restrict__ srcs, const int* __restrict__ dsts,
    int* __restrict__ cursor, int* __restrict__ nbr, int n_edges, int n_nodes)
{
    int e = blockIdx.x * 256 + threadIdx.x;
    if (e >= n_edges) return;
    int s = srcs[e], d = dsts[e];
    if ((unsigned)s >= (unsigned)n_nodes || (unsigned)d >= (unsigned)n_nodes) return;
    int pos = atomicAdd(&cursor[d], 1);
    nbr[pos] = s;
}

// ---------------------------------------------------------------------------
// Fused SAGE layer, MFMA edition. One wave per 16-node tile (grid-stride):
//   1) per node: gather-mean over CSR neighbors (lane=g*8+l: 8 neighbors in
//      parallel, 16B short8 loads, butterfly-reduce over g) -> bf16 row into
//      wave-private LDS tile.
//   2) A-frags (mean from LDS, self row from global) + preloaded weight
//      B-frags (registers) -> 16x mfma_f32_16x16x32_bf16, bias in acc init.
//   3) epilogue: ReLU -> h (bf16), or fused head: dot(w_out)+sigmoid -> out.
// XMODE 0: xin dtype per flag. XMODE 1: xin is bf16 h.
// ---------------------------------------------------------------------------
template <int XMODE, bool HEAD>
__global__ __launch_bounds__(256) void k_layer(
    const int* __restrict__ flag, const void* __restrict__ xin,
    const int* __restrict__ nbr, const int* __restrict__ rowptr,
    const int* __restrict__ deg,
    const void* __restrict__ w_l, const void* __restrict__ bias,
    const void* __restrict__ w_r,
    const void* __restrict__ w_out, const void* __restrict__ b_out,
    void* __restrict__ outp, int n_nodes)
{
    __shared__ unsigned short tiles[4][TILE * TROW];
    const int isbf = flag[0];
    const bool xbf = (XMODE == 1) ? true : (isbf != 0);

    const int lane = threadIdx.x & 63;
    const int wid  = threadIdx.x >> 6;
    const int n_ = lane & 15;      // MFMA col (outch) / node row at A
    const int q_ = lane >> 4;      // quad
    const int l8 = lane & 7;       // gather: channel group (8 ch, 16B)
    const int g8 = lane >> 3;      // gather: neighbor slot 0..7

    // ---- preload weight B-fragments: B[k][n] = w[n][k] ----
    // lane holds B[k=q_*8+j][n=n_] ; frag kc covers k in [kc*32, kc*32+32)
    short8 wlf[4][2], wrf[4][2];
    float bv[4], wov[4];
    #pragma unroll
    for (int t = 0; t < 4; t++) {
        int row = t * 16 + n_;                 // output channel
        if (isbf) {
            const unsigned short* wl = (const unsigned short*)w_l;
            const unsigned short* wr = (const unsigned short*)w_r;
            #pragma unroll
            for (int kc = 0; kc < 2; kc++) {
                int k0 = kc * 32 + q_ * 8;
                wlf[t][kc] = *(const short8*)(wl + row * CH + k0);
                wrf[t][kc] = *(const short8*)(wr + row * CH + k0);
            }
            bv[t] = bf2f(((const unsigned short*)bias)[row]);
            if (HEAD) wov[t] = bf2f(((const unsigned short*)w_out)[row]);
        } else {
            const float* wl = (const float*)w_l;
            const float* wr = (const float*)w_r;
            #pragma unroll
            for (int kc = 0; kc < 2; kc++) {
                int k0 = kc * 32 + q_ * 8;
                #pragma unroll
                for (int j = 0; j < 8; j++) {
                    wlf[t][kc][j] = (short)f2bf(wl[row * CH + k0 + j]);
                    wrf[t][kc][j] = (short)f2bf(wr[row * CH + k0 + j]);
                }
            }
            bv[t] = ((const float*)bias)[row];
            if (HEAD) wov[t] = ((const float*)w_out)[row];
        }
    }

    unsigned short* tile = tiles[wid];
    const unsigned short* xu = (const unsigned short*)xin;
    const float*          xf = (const float*)xin;

    int gw = blockIdx.x * 4 + wid;
    int nw = gridDim.x * 4;
    int n_tiles = (n_nodes + TILE - 1) / TILE;

    for (int tb = gw; tb < n_tiles; tb += nw) {
        int base = tb * TILE;
        // prefetch rowptr/deg for the 16 nodes of this tile
        int rp0 = 0, dg0 = 0;
        if (lane < 16) {
            int node = base + lane;
            if (node < n_nodes) { rp0 = rowptr[node]; dg0 = deg[node]; }
        }
        // ---- gather phase: one node at a time, 8 neighbors in parallel ----
        for (int mm = 0; mm < TILE; mm++) {
            int row = __shfl(rp0, mm);
            int d   = __shfl(dg0, mm);
            float aggv[8] = {0,0,0,0,0,0,0,0};
            for (int it0 = 0; it0 < d; it0 += 16) {
                int i0 = it0 + g8;
                int i1 = it0 + 8 + g8;
                if (i0 < d) {
                    int s = nbr[row + i0];
                    if (xbf) {
                        short8 v = *(const short8*)(xu + (size_t)s * CH + l8 * 8);
                        #pragma unroll
                        for (int j = 0; j < 8; j++) aggv[j] += bf2f((unsigned short)v[j]);
                    } else {
                        const float* p = xf + (size_t)s * CH + l8 * 8;
                        float4 a = *(const float4*)p, b = *(const float4*)(p + 4);
                        aggv[0] += a.x; aggv[1] += a.y; aggv[2] += a.z; aggv[3] += a.w;
                        aggv[4] += b.x; aggv[5] += b.y; aggv[6] += b.z; aggv[7] += b.w;
                    }
                }
                if (i1 < d) {
                    int s = nbr[row + i1];
                    if (xbf) {
                        short8 v = *(const short8*)(xu + (size_t)s * CH + l8 * 8);
                        #pragma unroll
                        for (int j = 0; j < 8; j++) aggv[j] += bf2f((unsigned short)v[j]);
                    } else {
                        const float* p = xf + (size_t)s * CH + l8 * 8;
                        float4 a = *(const float4*)p, b = *(const float4*)(p + 4);
                        aggv[0] += a.x; aggv[1] += a.y; aggv[2] += a.z; aggv[3] += a.w;
                        aggv[4] += b.x; aggv[5] += b.y; aggv[6] += b.z; aggv[7] += b.w;
                    }
                }
            }
            // reduce across the 8 neighbor slots (g-dim strides: 8,16,32)
            #pragma unroll
            for (int off = 8; off < 64; off <<= 1) {
                #pragma unroll
                for (int j = 0; j < 8; j++) aggv[j] += __shfl_xor(aggv[j], off);
            }
            float inv = 1.0f / (float)max(d, 1);
            if (lane < 8) {
                short8 mv;
                #pragma unroll
                for (int j = 0; j < 8; j++) mv[j] = (short)f2bf(aggv[j] * inv);
                *(short8*)(tile + mm * TROW + lane * 8) = mv;
            }
        }
        // ---- A fragments ----
        // A[m=n_][k=q_*8+j] (+32 for frag1); mean rows from LDS, self from global
        short8 am0 = *(const short8*)(tile + n_ * TROW + q_ * 8);
        short8 am1 = *(const short8*)(tile + n_ * TROW + 32 + q_ * 8);
        int node_m = base + n_;
        int node_c = (node_m < n_nodes) ? node_m : 0;
        short8 ax0, ax1;
        if (xbf) {
            ax0 = *(const short8*)(xu + (size_t)node_c * CH + q_ * 8);
            ax1 = *(const short8*)(xu + (size_t)node_c * CH + 32 + q_ * 8);
        } else {
            const float* p = xf + (size_t)node_c * CH;
            #pragma unroll
            for (int j = 0; j < 8; j++) {
                ax0[j] = (short)f2bf(p[q_ * 8 + j]);
                ax1[j] = (short)f2bf(p[32 + q_ * 8 + j]);
            }
        }
        // ---- MFMA: D = mean@Wl^T + x@Wr^T + bias ----
        floatx4 acc[4];
        #pragma unroll
        for (int t = 0; t < 4; t++) {
            acc[t] = (floatx4){bv[t], bv[t], bv[t], bv[t]};
            acc[t] = __builtin_amdgcn_mfma_f32_16x16x32_bf16(am0, wlf[t][0], acc[t], 0, 0, 0);
            acc[t] = __builtin_amdgcn_mfma_f32_16x16x32_bf16(am1, wlf[t][1], acc[t], 0, 0, 0);
            acc[t] = __builtin_amdgcn_mfma_f32_16x16x32_bf16(ax0, wrf[t][0], acc[t], 0, 0, 0);
            acc[t] = __builtin_amdgcn_mfma_f32_16x16x32_bf16(ax1, wrf[t][1], acc[t], 0, 0, 0);
        }
        // ---- epilogue: C/D layout col=lane&15, row=q_*4+reg ----
        if (!HEAD) {
            unsigned short* ho = (unsigned short*)outp;
            #pragma unroll
            for (int t = 0; t < 4; t++) {
                int c = t * 16 + n_;
                #pragma unroll
                for (int reg = 0; reg < 4; reg++) {
                    int node_r = base + q_ * 4 + reg;
                    if (node_r < n_nodes)
                        ho[(size_t)node_r * CH + c] = f2bf(fmaxf(acc[t][reg], 0.0f));
                }
            }
        } else {
            float p[4] = {0, 0, 0, 0};
            #pragma unroll
            for (int t = 0; t < 4; t++) {
                #pragma unroll
                for (int reg = 0; reg < 4; reg++)
                    p[reg] += fmaxf(acc[t][reg], 0.0f) * wov[t];
            }
            #pragma unroll
            for (int off = 1; off < 16; off <<= 1) {
                #pragma unroll
                for (int reg = 0; reg < 4; reg++)
                    p[reg] += __shfl_xor(p[reg], off);
            }
            if (n_ == 0) {
                float bo = isbf ? bf2f(((const unsigned short*)b_out)[0])
                                : ((const float*)b_out)[0];
                #pragma unroll
                for (int reg = 0; reg < 4; reg++) {
                    int node_r = base + q_ * 4 + reg;
                    if (node_r < n_nodes) {
                        float sg = 1.0f / (1.0f + expf(-(p[reg] + bo)));
                        if (isbf) ((unsigned short*)outp)[node_r] = f2bf(sg);
                        else      ((float*)outp)[node_r] = sg;
                    }
                }
            }
        }
    }
}

extern "C" void kernel_launch(void* const* d_in, const int* in_sizes, int n_in,
                              void* d_out, int out_size, void* d_ws, size_t ws_size,
                              hipStream_t stream)
{
    const void* x    = d_in[0];
    const int*  ei   = (const int*)d_in[1];
    const void* w1_l = d_in[2];
    const void* b1   = d_in[3];
    const void* w1_r = d_in[4];
    const void* w2_l = d_in[5];
    const void* b2   = d_in[6];
    const void* w2_r = d_in[7];
    const void* wout = d_in[8];
    const void* bout = d_in[9];

    int n_nodes = out_size;
    int n_edges = in_sizes[1] / 2;
    const int* srcs = ei;
    const int* dsts = ei + n_edges;

    // ws: [flag][deg n][rowptr n][cursor n][bsum 1024][nbr E][h n*64 bf16]
    char* wsb = (char*)d_ws;
    size_t off = 0;
    auto carve = [&](size_t bytes) { size_t p = off; off = (off + bytes + 255) & ~(size_t)255; return p; };
    size_t flag_off = carve(sizeof(int));
    size_t deg_off  = carve((size_t)n_nodes * sizeof(int));
    size_t row_off  = carve((size_t)n_nodes * sizeof(int));
    size_t cur_off  = carve((size_t)n_nodes * sizeof(int));
    size_t bs_off   = carve(1024 * sizeof(int));
    size_t nbr_off  = carve((size_t)n_edges * sizeof(int));
    size_t h_off    = carve((size_t)n_nodes * CH * sizeof(unsigned short));
    int* flag   = (int*)(wsb + flag_off);
    int* deg    = (int*)(wsb + deg_off);
    int* rowptr = (int*)(wsb + row_off);
    int* cursor = (int*)(wsb + cur_off);
    int* bsum   = (int*)(wsb + bs_off);
    int* nbr    = (int*)(wsb + nbr_off);
    void* h     = (void*)(wsb + h_off);

    int eblocks = (n_edges + 255) / 256;
    int nb1     = (n_nodes + 1023) / 1024;
    int n_tiles = (n_nodes + TILE - 1) / TILE;
    int lblocks = (n_tiles + 7) / 8;          // 2 tiles per wave

    k_detect<<<1, 64, 0, stream>>>((const unsigned short*)x, flag);
    hipMemsetAsync(deg, 0, (size_t)n_nodes * sizeof(int), stream);

    // CSR build
    k_hist<<<eblocks, 256, 0, stream>>>(dsts, deg, n_edges, n_nodes);
    k_scan1<<<nb1, 256, 0, stream>>>(deg, rowptr, bsum, n_nodes);
    k_scan2<<<1, 256, 0, stream>>>(bsum, nb1);
    k_scan3<<<nb1, 256, 0, stream>>>(rowptr, cursor, bsum, n_nodes);
    k_permute<<<eblocks, 256, 0, stream>>>(srcs, dsts, cursor, nbr, n_edges, n_nodes);

    // layer 1: x -> h (bf16)
    k_layer<0, false><<<lblocks, 256, 0, stream>>>(flag, x, nbr, rowptr, deg,
        w1_l, b1, w1_r, nullptr, nullptr, h, n_nodes);
    // layer 2 + head: h -> out
    k_layer<1, true><<<lblocks, 256, 0, stream>>>(flag, h, nbr, rowptr, deg,
        w2_l, b2, w2_r, wout, bout, d_out, n_nodes);
}

// Round 5
// 337.641 us; speedup vs baseline: 6.4588x; 1.2727x over previous
//
#include <hip/hip_runtime.h>
#include <hip/hip_bf16.h>
#include <math.h>

#define CH 64
#define TILE 16

typedef short short8 __attribute__((ext_vector_type(8)));
typedef float floatx4 __attribute__((ext_vector_type(4)));

__device__ __forceinline__ float bf2f(unsigned short u) {
    return __uint_as_float(((unsigned int)u) << 16);
}
__device__ __forceinline__ unsigned short f2bf(float f) {
    unsigned int x = __float_as_uint(f);
    unsigned int r = (x + 0x7fff + ((x >> 16) & 1)) >> 16;   // RNE
    return (unsigned short)r;
}

// ---------------------------------------------------------------------------
// Histogram of dst degrees; block 0 wave 0 also runs the dtype detector
// (bf16 flag=1 vs fp32 flag=0, exponent-sanity voting on x).
// ---------------------------------------------------------------------------
__global__ __launch_bounds__(256) void k_hist(
    const unsigned short* __restrict__ x,
    const int* __restrict__ dsts, int* __restrict__ deg, int* __restrict__ flag,
    int n_edges, int n_nodes)
{
    if (blockIdx.x == 0 && threadIdx.x < 64) {
        unsigned short u = x[2 * threadIdx.x];
        int ex = (u >> 7) & 0xFF;
        bool insane = (ex < 0x60) || (ex > 0x9F);
        unsigned long long m = __ballot(insane);
        if (threadIdx.x == 0) flag[0] = (__popcll(m) > 16) ? 0 : 1;
    }
    int e = blockIdx.x * 256 + threadIdx.x;
    if (e >= n_edges) return;
    int d = dsts[e];
    if ((unsigned)d < (unsigned)n_nodes) atomicAdd(&deg[d], 1);
}

// ---------------------------------------------------------------------------
// Exclusive scan: per-1024 block partials -> block-sum scan -> add-back.
// rowptr has n+1 entries; k_scan2 writes rowptr[n] = total.
// ---------------------------------------------------------------------------
__global__ __launch_bounds__(256) void k_scan1(
    const int* __restrict__ deg, int* __restrict__ rowptr,
    int* __restrict__ bsum, int n)
{
    __shared__ int ts[256];
    int t = threadIdx.x;
    int base = blockIdx.x * 1024 + t * 4;
    int v[4], local = 0;
    #pragma unroll
    for (int k = 0; k < 4; k++) { v[k] = (base + k < n) ? deg[base + k] : 0; local += v[k]; }
    ts[t] = local; __syncthreads();
    for (int off = 1; off < 256; off <<= 1) {
        int val = (t >= off) ? ts[t - off] : 0;
        __syncthreads();
        ts[t] += val;
        __syncthreads();
    }
    int run = ts[t] - local;
    #pragma unroll
    for (int k = 0; k < 4; k++) { if (base + k < n) rowptr[base + k] = run; run += v[k]; }
    if (t == 255) bsum[blockIdx.x] = ts[255];
}

__global__ __launch_bounds__(256) void k_scan2(
    int* __restrict__ bsum, int* __restrict__ rowptr, int nb, int n)
{
    __shared__ int ts[256];
    int t = threadIdx.x;
    int base = t * 4;
    int v[4], local = 0;
    #pragma unroll
    for (int k = 0; k < 4; k++) { v[k] = (base + k < nb) ? bsum[base + k] : 0; local += v[k]; }
    ts[t] = local; __syncthreads();
    for (int off = 1; off < 256; off <<= 1) {
        int val = (t >= off) ? ts[t - off] : 0;
        __syncthreads();
        ts[t] += val;
        __syncthreads();
    }
    int run = ts[t] - local;
    #pragma unroll
    for (int k = 0; k < 4; k++) { if (base + k < nb) bsum[base + k] = run; run += v[k]; }
    if (t == 255) rowptr[n] = ts[255];       // grand total
}

__global__ __launch_bounds__(256) void k_scan3(
    int* __restrict__ rowptr, int* __restrict__ cursor,
    const int* __restrict__ bsum, int n)
{
    int add = bsum[blockIdx.x];
    int base = blockIdx.x * 1024 + threadIdx.x * 4;
    #pragma unroll
    for (int k = 0; k < 4; k++) {
        int i = base + k;
        if (i < n) { int r = rowptr[i] + add; rowptr[i] = r; cursor[i] = r; }
    }
}

__global__ __launch_bounds__(256) void k_permute(
    const int* __restrict__ srcs, const int* __restrict__ dsts,
    int* __restrict__ cursor, int* __restrict__ nbr, int n_edges, int n_nodes)
{
    int e = blockIdx.x * 256 + threadIdx.x;
    if (e >= n_edges) return;
    int s = srcs[e], d = dsts[e];
    if ((unsigned)s >= (unsigned)n_nodes || (unsigned)d >= (unsigned)n_nodes) return;
    int pos = atomicAdd(&cursor[d], 1);
    nbr[pos] = s;
}

// ---------------------------------------------------------------------------
// Gather-mean: ONE WAVE PER NODE (high occupancy, high MLP).
// lane = g8 (neighbor slot 0..7) x l8 (channel chunk 0..7, 8ch/16B each).
// Two slots in flight per loop iter (i0, i0+8). Reduce across the 8 slots via
// a wave-private LDS round-trip (no barrier needed). Writes bf16 mean row.
// XMODE 0: xin dtype per flag. XMODE 1: xin is bf16.
// ---------------------------------------------------------------------------
template <int XMODE>
__global__ __launch_bounds__(256) void k_gather(
    const int* __restrict__ flag, const void* __restrict__ xin,
    const int* __restrict__ nbr, const int* __restrict__ rowptr,
    unsigned short* __restrict__ meanout, int n_nodes)
{
    __shared__ float red[4][8 * CH];         // 8 KB: per-wave 8 slots x 64 ch
    const bool xbf = (XMODE == 1) ? true : (flag[0] != 0);
    const int lane = threadIdx.x & 63;
    const int wid  = threadIdx.x >> 6;
    const int l8 = lane & 7;                 // channel chunk
    const int g8 = lane >> 3;                // neighbor slot

    int node = blockIdx.x * 4 + wid;
    if (node >= n_nodes) return;
    int row = rowptr[node];
    int d   = rowptr[node + 1] - row;

    const unsigned short* xu = (const unsigned short*)xin;
    const float*          xf = (const float*)xin;

    floatx4 a0 = {0, 0, 0, 0}, a1 = {0, 0, 0, 0};
    for (int it = 0; it < d; it += 16) {
        int i0 = it + g8;
        int i1 = it + 8 + g8;
        int s0 = (i0 < d) ? nbr[row + i0] : -1;
        int s1 = (i1 < d) ? nbr[row + i1] : -1;
        if (s0 >= 0) {
            if (xbf) {
                short8 v = *(const short8*)(xu + (size_t)s0 * CH + l8 * 8);
                #pragma unroll
                for (int j = 0; j < 4; j++) a0[j] += bf2f((unsigned short)v[j]);
                #pragma unroll
                for (int j = 0; j < 4; j++) a1[j] += bf2f((unsigned short)v[4 + j]);
            } else {
                const float* p = xf + (size_t)s0 * CH + l8 * 8;
                floatx4 u = *(const floatx4*)p, w = *(const floatx4*)(p + 4);
                a0 += u; a1 += w;
            }
        }
        if (s1 >= 0) {
            if (xbf) {
                short8 v = *(const short8*)(xu + (size_t)s1 * CH + l8 * 8);
                #pragma unroll
                for (int j = 0; j < 4; j++) a0[j] += bf2f((unsigned short)v[j]);
                #pragma unroll
                for (int j = 0; j < 4; j++) a1[j] += bf2f((unsigned short)v[4 + j]);
            } else {
                const float* p = xf + (size_t)s1 * CH + l8 * 8;
                floatx4 u = *(const floatx4*)p, w = *(const floatx4*)(p + 4);
                a0 += u; a1 += w;
            }
        }
    }

    // wave-private LDS reduce across the 8 neighbor slots
    float* rb = red[wid];
    *(floatx4*)&rb[g8 * CH + l8 * 8]     = a0;
    *(floatx4*)&rb[g8 * CH + l8 * 8 + 4] = a1;
    // same wave: compiler orders via lgkmcnt; banks: (g*64+lane)%32 = lane%32 -> conflict-free
    float s = 0.0f;
    #pragma unroll
    for (int g = 0; g < 8; g++) s += rb[g * CH + lane];
    float inv = 1.0f / (float)max(d, 1);
    meanout[(size_t)node * CH + lane] = f2bf(s * inv);
}

// ---------------------------------------------------------------------------
// MFMA tile kernel: 16-node tile per wave.
//   D = mean@Wl^T + x_self@Wr^T + bias ; ReLU -> h, or fused head -> out.
// Weight B-frags preloaded to registers; A-frags streamed from mean/x.
// C/D layout: col = lane&15, row = (lane>>4)*4 + reg  (verified round 4).
// ---------------------------------------------------------------------------
template <int XMODE, bool HEAD>
__global__ __launch_bounds__(256) void k_mm(
    const int* __restrict__ flag, const void* __restrict__ xin,
    const unsigned short* __restrict__ meanin,
    const void* __restrict__ w_l, const void* __restrict__ bias,
    const void* __restrict__ w_r,
    const void* __restrict__ w_out, const void* __restrict__ b_out,
    void* __restrict__ outp, int n_nodes)
{
    const int isbf = flag[0];
    const bool xbf = (XMODE == 1) ? true : (isbf != 0);
    const int lane = threadIdx.x & 63;
    const int wid  = threadIdx.x >> 6;
    const int n_ = lane & 15;
    const int q_ = lane >> 4;

    // preload weight B-frags: lane holds B[k=q_*8+j][n=n_], frag kc: k0=kc*32
    short8 wlf[4][2], wrf[4][2];
    float bv[4], wov[4];
    #pragma unroll
    for (int t = 0; t < 4; t++) {
        int row = t * 16 + n_;
        if (isbf) {
            const unsigned short* wl = (const unsigned short*)w_l;
            const unsigned short* wr = (const unsigned short*)w_r;
            #pragma unroll
            for (int kc = 0; kc < 2; kc++) {
                int k0 = kc * 32 + q_ * 8;
                wlf[t][kc] = *(const short8*)(wl + row * CH + k0);
                wrf[t][kc] = *(const short8*)(wr + row * CH + k0);
            }
            bv[t] = bf2f(((const unsigned short*)bias)[row]);
            if (HEAD) wov[t] = bf2f(((const unsigned short*)w_out)[row]);
        } else {
            const float* wl = (const float*)w_l;
            const float* wr = (const float*)w_r;
            #pragma unroll
            for (int kc = 0; kc < 2; kc++) {
                int k0 = kc * 32 + q_ * 8;
                #pragma unroll
                for (int j = 0; j < 8; j++) {
                    wlf[t][kc][j] = (short)f2bf(wl[row * CH + k0 + j]);
                    wrf[t][kc][j] = (short)f2bf(wr[row * CH + k0 + j]);
                }
            }
            bv[t] = ((const float*)bias)[row];
            if (HEAD) wov[t] = ((const float*)w_out)[row];
        }
    }

    const unsigned short* xu = (const unsigned short*)xin;
    const float*          xf = (const float*)xin;
    int n_tiles = (n_nodes + TILE - 1) / TILE;
    int gw = blockIdx.x * 4 + wid;
    int nw = gridDim.x * 4;

    for (int tb = gw; tb < n_tiles; tb += nw) {
        int base = tb * TILE;
        int node_m = base + n_;
        int node_c = (node_m < n_nodes) ? node_m : 0;
        // A-frags: mean rows (bf16 ws) + self rows
        short8 am0 = *(const short8*)(meanin + (size_t)node_c * CH + q_ * 8);
        short8 am1 = *(const short8*)(meanin + (size_t)node_c * CH + 32 + q_ * 8);
        short8 ax0, ax1;
        if (xbf) {
            ax0 = *(const short8*)(xu + (size_t)node_c * CH + q_ * 8);
            ax1 = *(const short8*)(xu + (size_t)node_c * CH + 32 + q_ * 8);
        } else {
            const float* p = xf + (size_t)node_c * CH;
            #pragma unroll
            for (int j = 0; j < 8; j++) {
                ax0[j] = (short)f2bf(p[q_ * 8 + j]);
                ax1[j] = (short)f2bf(p[32 + q_ * 8 + j]);
            }
        }
        floatx4 acc[4];
        #pragma unroll
        for (int t = 0; t < 4; t++) {
            acc[t] = (floatx4){bv[t], bv[t], bv[t], bv[t]};
            acc[t] = __builtin_amdgcn_mfma_f32_16x16x32_bf16(am0, wlf[t][0], acc[t], 0, 0, 0);
            acc[t] = __builtin_amdgcn_mfma_f32_16x16x32_bf16(am1, wlf[t][1], acc[t], 0, 0, 0);
            acc[t] = __builtin_amdgcn_mfma_f32_16x16x32_bf16(ax0, wrf[t][0], acc[t], 0, 0, 0);
            acc[t] = __builtin_amdgcn_mfma_f32_16x16x32_bf16(ax1, wrf[t][1], acc[t], 0, 0, 0);
        }
        if (!HEAD) {
            unsigned short* ho = (unsigned short*)outp;
            #pragma unroll
            for (int t = 0; t < 4; t++) {
                int c = t * 16 + n_;
                #pragma unroll
                for (int reg = 0; reg < 4; reg++) {
                    int node_r = base + q_ * 4 + reg;
                    if (node_r < n_nodes)
                        ho[(size_t)node_r * CH + c] = f2bf(fmaxf(acc[t][reg], 0.0f));
                }
            }
        } else {
            float p[4] = {0, 0, 0, 0};
            #pragma unroll
            for (int t = 0; t < 4; t++) {
                #pragma unroll
                for (int reg = 0; reg < 4; reg++)
                    p[reg] += fmaxf(acc[t][reg], 0.0f) * wov[t];
            }
            #pragma unroll
            for (int off = 1; off < 16; off <<= 1) {
                #pragma unroll
                for (int reg = 0; reg < 4; reg++)
                    p[reg] += __shfl_xor(p[reg], off);
            }
            if (n_ == 0) {
                float bo = isbf ? bf2f(((const unsigned short*)b_out)[0])
                                : ((const float*)b_out)[0];
                #pragma unroll
                for (int reg = 0; reg < 4; reg++) {
                    int node_r = base + q_ * 4 + reg;
                    if (node_r < n_nodes) {
                        float sg = 1.0f / (1.0f + expf(-(p[reg] + bo)));
                        if (isbf) ((unsigned short*)outp)[node_r] = f2bf(sg);
                        else      ((float*)outp)[node_r] = sg;
                    }
                }
            }
        }
    }
}

extern "C" void kernel_launch(void* const* d_in, const int* in_sizes, int n_in,
                              void* d_out, int out_size, void* d_ws, size_t ws_size,
                              hipStream_t stream)
{
    const void* x    = d_in[0];
    const int*  ei   = (const int*)d_in[1];
    const void* w1_l = d_in[2];
    const void* b1   = d_in[3];
    const void* w1_r = d_in[4];
    const void* w2_l = d_in[5];
    const void* b2   = d_in[6];
    const void* w2_r = d_in[7];
    const void* wout = d_in[8];
    const void* bout = d_in[9];

    int n_nodes = out_size;
    int n_edges = in_sizes[1] / 2;
    const int* srcs = ei;
    const int* dsts = ei + n_edges;

    // ws: [flag][deg n][rowptr n+1][cursor n][bsum 1024][nbr E][mean n*64 bf16][h n*64 bf16]
    char* wsb = (char*)d_ws;
    size_t off = 0;
    auto carve = [&](size_t bytes) { size_t p = off; off = (off + bytes + 255) & ~(size_t)255; return p; };
    size_t flag_off = carve(sizeof(int));
    size_t deg_off  = carve((size_t)n_nodes * sizeof(int));
    size_t row_off  = carve((size_t)(n_nodes + 1) * sizeof(int));
    size_t cur_off  = carve((size_t)n_nodes * sizeof(int));
    size_t bs_off   = carve(1024 * sizeof(int));
    size_t nbr_off  = carve((size_t)n_edges * sizeof(int));
    size_t mean_off = carve((size_t)n_nodes * CH * sizeof(unsigned short));
    size_t h_off    = carve((size_t)n_nodes * CH * sizeof(unsigned short));
    int* flag   = (int*)(wsb + flag_off);
    int* deg    = (int*)(wsb + deg_off);
    int* rowptr = (int*)(wsb + row_off);
    int* cursor = (int*)(wsb + cur_off);
    int* bsum   = (int*)(wsb + bs_off);
    int* nbr    = (int*)(wsb + nbr_off);
    unsigned short* mean = (unsigned short*)(wsb + mean_off);
    unsigned short* h    = (unsigned short*)(wsb + h_off);

    int eblocks = (n_edges + 255) / 256;
    int nb1     = (n_nodes + 1023) / 1024;
    int n_tiles = (n_nodes + TILE - 1) / TILE;
    int gblocks = (n_nodes + 3) / 4;          // k_gather: 1 wave per node
    int mblocks = (n_tiles + 3) / 4;          // k_mm: 1 wave per tile

    hipMemsetAsync(deg, 0, (size_t)n_nodes * sizeof(int), stream);

    // CSR build (+ dtype detect inside k_hist)
    k_hist<<<eblocks, 256, 0, stream>>>((const unsigned short*)x, dsts, deg, flag, n_edges, n_nodes);
    k_scan1<<<nb1, 256, 0, stream>>>(deg, rowptr, bsum, n_nodes);
    k_scan2<<<1, 256, 0, stream>>>(bsum, rowptr, nb1, n_nodes);
    k_scan3<<<nb1, 256, 0, stream>>>(rowptr, cursor, bsum, n_nodes);
    k_permute<<<eblocks, 256, 0, stream>>>(srcs, dsts, cursor, nbr, n_edges, n_nodes);

    // layer 1: x -> h
    k_gather<0><<<gblocks, 256, 0, stream>>>(flag, x, nbr, rowptr, mean, n_nodes);
    k_mm<0, false><<<mblocks, 256, 0, stream>>>(flag, x, mean, w1_l, b1, w1_r,
                                                nullptr, nullptr, h, n_nodes);
    // layer 2 + head: h -> out
    k_gather<1><<<gblocks, 256, 0, stream>>>(flag, h, nbr, rowptr, mean, n_nodes);
    k_mm<1, true><<<mblocks, 256, 0, stream>>>(flag, h, mean, w2_l, b2, w2_r,
                                               wout, bout, d_out, n_nodes);
}

// Round 6
// 284.300 us; speedup vs baseline: 7.6706x; 1.1876x over previous
//
#include <hip/hip_runtime.h>
#include <hip/hip_bf16.h>
#include <math.h>

#define CH 64
#define TILE 16
#define BSHIFT 13   // permute dst-band size: 8192 nodes (~330 KB nbr slice)

typedef short short8 __attribute__((ext_vector_type(8)));
typedef float floatx4 __attribute__((ext_vector_type(4)));

__device__ __forceinline__ float bf2f(unsigned short u) {
    return __uint_as_float(((unsigned int)u) << 16);
}
__device__ __forceinline__ unsigned short f2bf(float f) {
    unsigned int x = __float_as_uint(f);
    unsigned int r = (x + 0x7fff + ((x >> 16) & 1)) >> 16;   // RNE
    return (unsigned short)r;
}

// ---------------------------------------------------------------------------
// Histogram of dst degrees; block 0 wave 0 also runs the dtype detector
// (bf16 flag=1 vs fp32 flag=0, exponent-sanity voting on x).
// ---------------------------------------------------------------------------
__global__ __launch_bounds__(256) void k_hist(
    const unsigned short* __restrict__ x,
    const int* __restrict__ dsts, int* __restrict__ deg, int* __restrict__ flag,
    int n_edges, int n_nodes)
{
    if (blockIdx.x == 0 && threadIdx.x < 64) {
        unsigned short u = x[2 * threadIdx.x];
        int ex = (u >> 7) & 0xFF;
        bool insane = (ex < 0x60) || (ex > 0x9F);
        unsigned long long m = __ballot(insane);
        if (threadIdx.x == 0) flag[0] = (__popcll(m) > 16) ? 0 : 1;
    }
    int e = blockIdx.x * 256 + threadIdx.x;
    if (e >= n_edges) return;
    int d = dsts[e];
    if ((unsigned)d < (unsigned)n_nodes) atomicAdd(&deg[d], 1);
}

// ---------------------------------------------------------------------------
// Exclusive scan: per-1024 block partials -> block-sum scan -> add-back.
// rowptr has n+1 entries; k_scan2 writes rowptr[n] = total.
// ---------------------------------------------------------------------------
__global__ __launch_bounds__(256) void k_scan1(
    const int* __restrict__ deg, int* __restrict__ rowptr,
    int* __restrict__ bsum, int n)
{
    __shared__ int ts[256];
    int t = threadIdx.x;
    int base = blockIdx.x * 1024 + t * 4;
    int v[4], local = 0;
    #pragma unroll
    for (int k = 0; k < 4; k++) { v[k] = (base + k < n) ? deg[base + k] : 0; local += v[k]; }
    ts[t] = local; __syncthreads();
    for (int off = 1; off < 256; off <<= 1) {
        int val = (t >= off) ? ts[t - off] : 0;
        __syncthreads();
        ts[t] += val;
        __syncthreads();
    }
    int run = ts[t] - local;
    #pragma unroll
    for (int k = 0; k < 4; k++) { if (base + k < n) rowptr[base + k] = run; run += v[k]; }
    if (t == 255) bsum[blockIdx.x] = ts[255];
}

__global__ __launch_bounds__(256) void k_scan2(
    int* __restrict__ bsum, int* __restrict__ rowptr, int nb, int n)
{
    __shared__ int ts[256];
    int t = threadIdx.x;
    int base = t * 4;
    int v[4], local = 0;
    #pragma unroll
    for (int k = 0; k < 4; k++) { v[k] = (base + k < nb) ? bsum[base + k] : 0; local += v[k]; }
    ts[t] = local; __syncthreads();
    for (int off = 1; off < 256; off <<= 1) {
        int val = (t >= off) ? ts[t - off] : 0;
        __syncthreads();
        ts[t] += val;
        __syncthreads();
    }
    int run = ts[t] - local;
    #pragma unroll
    for (int k = 0; k < 4; k++) { if (base + k < nb) bsum[base + k] = run; run += v[k]; }
    if (t == 255) rowptr[n] = ts[255];       // grand total
}

__global__ __launch_bounds__(256) void k_scan3(
    int* __restrict__ rowptr, int* __restrict__ cursor,
    const int* __restrict__ bsum, int n)
{
    int add = bsum[blockIdx.x];
    int base = blockIdx.x * 1024 + threadIdx.x * 4;
    #pragma unroll
    for (int k = 0; k < 4; k++) {
        int i = base + k;
        if (i < n) { int r = rowptr[i] + add; rowptr[i] = r; cursor[i] = r; }
    }
}

// ---------------------------------------------------------------------------
// Banded permute: each thread register-caches 4 edges (single read of
// srcs/dsts), then loops over dst-bands of 8192 nodes committing only the
// edges in the current band. All concurrent nbr writes land in a ~330 KB
// slice -> L2-resident lines coalesce ~16 entries before writeback
// (vs 1 entry/line = 70 MB HBM writes in the unbanded version).
// ---------------------------------------------------------------------------
__global__ __launch_bounds__(256) void k_permute(
    const int* __restrict__ srcs, const int* __restrict__ dsts,
    int* __restrict__ cursor, int* __restrict__ nbr, int n_edges, int n_nodes)
{
    const int nth = gridDim.x * 256;
    const int t = blockIdx.x * 256 + threadIdx.x;
    int s[4], d[4];
    #pragma unroll
    for (int k = 0; k < 4; k++) {
        int e = t + k * nth;
        if (e < n_edges) {
            int ss = srcs[e], dd = dsts[e];
            s[k] = ss;
            d[k] = ((unsigned)ss < (unsigned)n_nodes && (unsigned)dd < (unsigned)n_nodes)
                 ? dd : -1;
        } else {
            d[k] = -1;
        }
    }
    const int nbands = (n_nodes + (1 << BSHIFT) - 1) >> BSHIFT;
    for (int b = 0; b < nbands; b++) {
        #pragma unroll
        for (int k = 0; k < 4; k++) {
            if (d[k] >= 0 && (d[k] >> BSHIFT) == b) {
                int pos = atomicAdd(&cursor[d[k]], 1);
                nbr[pos] = s[k];
            }
        }
    }
}

// ---------------------------------------------------------------------------
// Gather-mean: ONE WAVE PER NODE (high occupancy, high MLP).
// lane = g8 (neighbor slot 0..7) x l8 (channel chunk 0..7, 8ch/16B each).
// Two slots in flight per loop iter (i0, i0+8). Reduce across the 8 slots via
// a wave-private LDS round-trip (no barrier needed). Writes bf16 mean row.
// XMODE 0: xin dtype per flag. XMODE 1: xin is bf16.
// ---------------------------------------------------------------------------
template <int XMODE>
__global__ __launch_bounds__(256) void k_gather(
    const int* __restrict__ flag, const void* __restrict__ xin,
    const int* __restrict__ nbr, const int* __restrict__ rowptr,
    unsigned short* __restrict__ meanout, int n_nodes)
{
    __shared__ float red[4][8 * CH];         // 8 KB: per-wave 8 slots x 64 ch
    const bool xbf = (XMODE == 1) ? true : (flag[0] != 0);
    const int lane = threadIdx.x & 63;
    const int wid  = threadIdx.x >> 6;
    const int l8 = lane & 7;                 // channel chunk
    const int g8 = lane >> 3;                // neighbor slot

    int node = blockIdx.x * 4 + wid;
    if (node >= n_nodes) return;
    int row = rowptr[node];
    int d   = rowptr[node + 1] - row;

    const unsigned short* xu = (const unsigned short*)xin;
    const float*          xf = (const float*)xin;

    floatx4 a0 = {0, 0, 0, 0}, a1 = {0, 0, 0, 0};
    for (int it = 0; it < d; it += 16) {
        int i0 = it + g8;
        int i1 = it + 8 + g8;
        int s0 = (i0 < d) ? nbr[row + i0] : -1;
        int s1 = (i1 < d) ? nbr[row + i1] : -1;
        if (s0 >= 0) {
            if (xbf) {
                short8 v = *(const short8*)(xu + (size_t)s0 * CH + l8 * 8);
                #pragma unroll
                for (int j = 0; j < 4; j++) a0[j] += bf2f((unsigned short)v[j]);
                #pragma unroll
                for (int j = 0; j < 4; j++) a1[j] += bf2f((unsigned short)v[4 + j]);
            } else {
                const float* p = xf + (size_t)s0 * CH + l8 * 8;
                floatx4 u = *(const floatx4*)p, w = *(const floatx4*)(p + 4);
                a0 += u; a1 += w;
            }
        }
        if (s1 >= 0) {
            if (xbf) {
                short8 v = *(const short8*)(xu + (size_t)s1 * CH + l8 * 8);
                #pragma unroll
                for (int j = 0; j < 4; j++) a0[j] += bf2f((unsigned short)v[j]);
                #pragma unroll
                for (int j = 0; j < 4; j++) a1[j] += bf2f((unsigned short)v[4 + j]);
            } else {
                const float* p = xf + (size_t)s1 * CH + l8 * 8;
                floatx4 u = *(const floatx4*)p, w = *(const floatx4*)(p + 4);
                a0 += u; a1 += w;
            }
        }
    }

    // wave-private LDS reduce across the 8 neighbor slots
    float* rb = red[wid];
    *(floatx4*)&rb[g8 * CH + l8 * 8]     = a0;
    *(floatx4*)&rb[g8 * CH + l8 * 8 + 4] = a1;
    // same wave: compiler orders via lgkmcnt; banks: lane%32 -> conflict-free
    float s = 0.0f;
    #pragma unroll
    for (int g = 0; g < 8; g++) s += rb[g * CH + lane];
    float inv = 1.0f / (float)max(d, 1);
    meanout[(size_t)node * CH + lane] = f2bf(s * inv);
}

// ---------------------------------------------------------------------------
// MFMA tile kernel: 16-node tile per wave (grid-stride, ~3 tiles/wave).
//   D = mean@Wl^T + x_self@Wr^T + bias ; ReLU -> h, or fused head -> out.
// Weight B-frags preloaded to registers; A-frags streamed from mean/x.
// C/D layout: col = lane&15, row = (lane>>4)*4 + reg  (verified round 4).
// ---------------------------------------------------------------------------
template <int XMODE, bool HEAD>
__global__ __launch_bounds__(256) void k_mm(
    const int* __restrict__ flag, const void* __restrict__ xin,
    const unsigned short* __restrict__ meanin,
    const void* __restrict__ w_l, const void* __restrict__ bias,
    const void* __restrict__ w_r,
    const void* __restrict__ w_out, const void* __restrict__ b_out,
    void* __restrict__ outp, int n_nodes)
{
    const int isbf = flag[0];
    const bool xbf = (XMODE == 1) ? true : (isbf != 0);
    const int lane = threadIdx.x & 63;
    const int wid  = threadIdx.x >> 6;
    const int n_ = lane & 15;
    const int q_ = lane >> 4;

    // preload weight B-frags: lane holds B[k=q_*8+j][n=n_], frag kc: k0=kc*32
    short8 wlf[4][2], wrf[4][2];
    float bv[4], wov[4];
    #pragma unroll
    for (int t = 0; t < 4; t++) {
        int row = t * 16 + n_;
        if (isbf) {
            const unsigned short* wl = (const unsigned short*)w_l;
            const unsigned short* wr = (const unsigned short*)w_r;
            #pragma unroll
            for (int kc = 0; kc < 2; kc++) {
                int k0 = kc * 32 + q_ * 8;
                wlf[t][kc] = *(const short8*)(wl + row * CH + k0);
                wrf[t][kc] = *(const short8*)(wr + row * CH + k0);
            }
            bv[t] = bf2f(((const unsigned short*)bias)[row]);
            if (HEAD) wov[t] = bf2f(((const unsigned short*)w_out)[row]);
        } else {
            const float* wl = (const float*)w_l;
            const float* wr = (const float*)w_r;
            #pragma unroll
            for (int kc = 0; kc < 2; kc++) {
                int k0 = kc * 32 + q_ * 8;
                #pragma unroll
                for (int j = 0; j < 8; j++) {
                    wlf[t][kc][j] = (short)f2bf(wl[row * CH + k0 + j]);
                    wrf[t][kc][j] = (short)f2bf(wr[row * CH + k0 + j]);
                }
            }
            bv[t] = ((const float*)bias)[row];
            if (HEAD) wov[t] = ((const float*)w_out)[row];
        }
    }

    const unsigned short* xu = (const unsigned short*)xin;
    const float*          xf = (const float*)xin;
    int n_tiles = (n_nodes + TILE - 1) / TILE;
    int gw = blockIdx.x * 4 + wid;
    int nw = gridDim.x * 4;

    for (int tb = gw; tb < n_tiles; tb += nw) {
        int base = tb * TILE;
        int node_m = base + n_;
        int node_c = (node_m < n_nodes) ? node_m : 0;
        // A-frags: mean rows (bf16 ws) + self rows
        short8 am0 = *(const short8*)(meanin + (size_t)node_c * CH + q_ * 8);
        short8 am1 = *(const short8*)(meanin + (size_t)node_c * CH + 32 + q_ * 8);
        short8 ax0, ax1;
        if (xbf) {
            ax0 = *(const short8*)(xu + (size_t)node_c * CH + q_ * 8);
            ax1 = *(const short8*)(xu + (size_t)node_c * CH + 32 + q_ * 8);
        } else {
            const float* p = xf + (size_t)node_c * CH;
            #pragma unroll
            for (int j = 0; j < 8; j++) {
                ax0[j] = (short)f2bf(p[q_ * 8 + j]);
                ax1[j] = (short)f2bf(p[32 + q_ * 8 + j]);
            }
        }
        floatx4 acc[4];
        #pragma unroll
        for (int t = 0; t < 4; t++) {
            acc[t] = (floatx4){bv[t], bv[t], bv[t], bv[t]};
            acc[t] = __builtin_amdgcn_mfma_f32_16x16x32_bf16(am0, wlf[t][0], acc[t], 0, 0, 0);
            acc[t] = __builtin_amdgcn_mfma_f32_16x16x32_bf16(am1, wlf[t][1], acc[t], 0, 0, 0);
            acc[t] = __builtin_amdgcn_mfma_f32_16x16x32_bf16(ax0, wrf[t][0], acc[t], 0, 0, 0);
            acc[t] = __builtin_amdgcn_mfma_f32_16x16x32_bf16(ax1, wrf[t][1], acc[t], 0, 0, 0);
        }
        if (!HEAD) {
            unsigned short* ho = (unsigned short*)outp;
            #pragma unroll
            for (int t = 0; t < 4; t++) {
                int c = t * 16 + n_;
                #pragma unroll
                for (int reg = 0; reg < 4; reg++) {
                    int node_r = base + q_ * 4 + reg;
                    if (node_r < n_nodes)
                        ho[(size_t)node_r * CH + c] = f2bf(fmaxf(acc[t][reg], 0.0f));
                }
            }
        } else {
            float p[4] = {0, 0, 0, 0};
            #pragma unroll
            for (int t = 0; t < 4; t++) {
                #pragma unroll
                for (int reg = 0; reg < 4; reg++)
                    p[reg] += fmaxf(acc[t][reg], 0.0f) * wov[t];
            }
            #pragma unroll
            for (int off = 1; off < 16; off <<= 1) {
                #pragma unroll
                for (int reg = 0; reg < 4; reg++)
                    p[reg] += __shfl_xor(p[reg], off);
            }
            if (n_ == 0) {
                float bo = isbf ? bf2f(((const unsigned short*)b_out)[0])
                                : ((const float*)b_out)[0];
                #pragma unroll
                for (int reg = 0; reg < 4; reg++) {
                    int node_r = base + q_ * 4 + reg;
                    if (node_r < n_nodes) {
                        float sg = 1.0f / (1.0f + expf(-(p[reg] + bo)));
                        if (isbf) ((unsigned short*)outp)[node_r] = f2bf(sg);
                        else      ((float*)outp)[node_r] = sg;
                    }
                }
            }
        }
    }
}

extern "C" void kernel_launch(void* const* d_in, const int* in_sizes, int n_in,
                              void* d_out, int out_size, void* d_ws, size_t ws_size,
                              hipStream_t stream)
{
    const void* x    = d_in[0];
    const int*  ei   = (const int*)d_in[1];
    const void* w1_l = d_in[2];
    const void* b1   = d_in[3];
    const void* w1_r = d_in[4];
    const void* w2_l = d_in[5];
    const void* b2   = d_in[6];
    const void* w2_r = d_in[7];
    const void* wout = d_in[8];
    const void* bout = d_in[9];

    int n_nodes = out_size;
    int n_edges = in_sizes[1] / 2;
    const int* srcs = ei;
    const int* dsts = ei + n_edges;

    // ws: [flag][deg n][rowptr n+1][cursor n][bsum 1024][nbr E][mean n*64 bf16][h n*64 bf16]
    char* wsb = (char*)d_ws;
    size_t off = 0;
    auto carve = [&](size_t bytes) { size_t p = off; off = (off + bytes + 255) & ~(size_t)255; return p; };
    size_t flag_off = carve(sizeof(int));
    size_t deg_off  = carve((size_t)n_nodes * sizeof(int));
    size_t row_off  = carve((size_t)(n_nodes + 1) * sizeof(int));
    size_t cur_off  = carve((size_t)n_nodes * sizeof(int));
    size_t bs_off   = carve(1024 * sizeof(int));
    size_t nbr_off  = carve((size_t)n_edges * sizeof(int));
    size_t mean_off = carve((size_t)n_nodes * CH * sizeof(unsigned short));
    size_t h_off    = carve((size_t)n_nodes * CH * sizeof(unsigned short));
    int* flag   = (int*)(wsb + flag_off);
    int* deg    = (int*)(wsb + deg_off);
    int* rowptr = (int*)(wsb + row_off);
    int* cursor = (int*)(wsb + cur_off);
    int* bsum   = (int*)(wsb + bs_off);
    int* nbr    = (int*)(wsb + nbr_off);
    unsigned short* mean = (unsigned short*)(wsb + mean_off);
    unsigned short* h    = (unsigned short*)(wsb + h_off);

    int eblocks = (n_edges + 255) / 256;
    int pblocks = (n_edges + 1023) / 1024;    // 4 edges per thread
    int nb1     = (n_nodes + 1023) / 1024;
    int n_tiles = (n_nodes + TILE - 1) / TILE;
    int gblocks = (n_nodes + 3) / 4;          // k_gather: 1 wave per node
    int mblocks = 512;                        // k_mm: grid-stride over tiles

    hipMemsetAsync(deg, 0, (size_t)n_nodes * sizeof(int), stream);

    // CSR build (+ dtype detect inside k_hist)
    k_hist<<<eblocks, 256, 0, stream>>>((const unsigned short*)x, dsts, deg, flag, n_edges, n_nodes);
    k_scan1<<<nb1, 256, 0, stream>>>(deg, rowptr, bsum, n_nodes);
    k_scan2<<<1, 256, 0, stream>>>(bsum, rowptr, nb1, n_nodes);
    k_scan3<<<nb1, 256, 0, stream>>>(rowptr, cursor, bsum, n_nodes);
    k_permute<<<pblocks, 256, 0, stream>>>(srcs, dsts, cursor, nbr, n_edges, n_nodes);

    // layer 1: x -> h
    k_gather<0><<<gblocks, 256, 0, stream>>>(flag, x, nbr, rowptr, mean, n_nodes);
    k_mm<0, false><<<mblocks, 256, 0, stream>>>(flag, x, mean, w1_l, b1, w1_r,
                                                nullptr, nullptr, h, n_nodes);
    // layer 2 + head: h -> out
    k_gather<1><<<gblocks, 256, 0, stream>>>(flag, h, nbr, rowptr, mean, n_nodes);
    k_mm<1, true><<<mblocks, 256, 0, stream>>>(flag, h, mean, w2_l, b2, w2_r,
                                               wout, bout, d_out, n_nodes);
}